// Round 11
// baseline (73.880 us; speedup 1.0000x reference)
//
#include <hip/hip_runtime.h>

// Radius search (L2^2), single segment, M=4096 queries x N=8192 points.
// Out (float32, concat): [0,MN) packed idx (pad -1) | [MN,MN+M+1) row splits |
//                        [MN+M+1, 2MN+M+1) packed d2 (pad 0).
// Exact numpy fp32 op order (NO fma):
//   q2=(qx*qx+qy*qy)+qz*qz ; p2=(px*px+py*py)+pz*pz ; qp=(qx*px+qy*py)+qz*pz
//   d2=max((q2+p2)-2*qp, 0) ; mask: d2<=r*r  (max irrelevant for mask, r2>0)
//
// R10 (64us) put ALL 268MB of pad stores in K1 while K2 ran with an idle
// store pipe. R11 balances: K1 = count + idx-fill (138MB); K2 = scan, then
// dist-PAD fill [total,MN) (134MB, no overlap with packed region -> no race)
// woven with the mask pack. ~20us of store work per kernel.

typedef float f32x4 __attribute__((ext_vector_type(4)));

__device__ __forceinline__ void fill_region(float* __restrict__ base, long long n,
                                            float val, long long tid, long long nth) {
    long long head = (long long)(((16u - ((unsigned)(size_t)base & 15u)) & 15u) >> 2);
    if (head > n) head = n;
    for (long long i = tid; i < head; i += nth) base[i] = val;
    long long nv = (n - head) >> 2;
    f32x4* v = (f32x4*)(base + head);
    f32x4 vv = {val, val, val, val};
    for (long long i = tid; i < nv; i += nth) v[i] = vv;
    for (long long i = head + (nv << 2) + tid; i < n; i += nth) base[i] = val;
}

// ---------------- K1: fused count (4pt/lane) + woven idx-fill ----------------
__global__ __launch_bounds__(256) void rs_fused(
    const float* __restrict__ pts, const float* __restrict__ qs,
    const float* __restrict__ rad, int* __restrict__ counts,
    unsigned long long* __restrict__ masks, int storeMasks,
    float* __restrict__ out_idx, long long MN, int N, int M) {
    int t = threadIdx.x;
    int wv = t >> 6, lane = t & 63;
    int gw = blockIdx.x * 4 + wv;       // wave id == query id
    int nWaves = gridDim.x * 4;

    bool hasQ = (gw < M);
    int qc = hasQ ? gw : 0;
    float qx = qs[3 * qc], qy = qs[3 * qc + 1], qz = qs[3 * qc + 2];
    float q2 = __fadd_rn(__fadd_rn(__fmul_rn(qx, qx), __fmul_rn(qy, qy)),
                         __fmul_rn(qz, qz));
    float r = rad[qc];
    float r2 = hasQ ? __fmul_rn(r, r) : -1.0f;  // raw d2 > -1 always

    int nc = N >> 6;                      // 64-pt mask words
    int countIters = (N + 255) >> 8;      // 4 pts/lane/iter
    long long V = MN >> 2;                // MN % 4 == 0 in harness
    long long perWave = (V + nWaves - 1) / nWaves;
    int fillIters = (int)((perWave + 63) >> 6);
    long long fbase = (long long)gw * perWave;
    long long fend = fbase + perWave;
    if (fend > V) fend = V;
    f32x4* vidx = (f32x4*)out_idx;
    f32x4 vm1 = {-1.0f, -1.0f, -1.0f, -1.0f};

    int iters = countIters > fillIters ? countIters : fillIters;
    int cnt = 0;

    for (int it = 0; it < iters; ++it) {
        // ---- fill step: fire-and-forget coalesced idx stores ----
        if (it < fillIters) {
            long long fi = fbase + (long long)it * 64 + lane;
            if (fi < fend) vidx[fi] = vm1;
        }
        // ---- count step: 4 points per lane, independent loads ----
        if (it < countIters) {
            int p0 = (it << 8) + lane;
            float px[4], py[4], pz[4];
            bool vld[4];
#pragma unroll
            for (int k = 0; k < 4; ++k) {
                int p = p0 + (k << 6);
                vld[k] = (p < N);
                int pcl = vld[k] ? p : 0;
                px[k] = pts[3 * pcl];
                py[k] = pts[3 * pcl + 1];
                pz[k] = pts[3 * pcl + 2];
            }
#pragma unroll
            for (int k = 0; k < 4; ++k) {
                float p2 = __fadd_rn(
                    __fadd_rn(__fmul_rn(px[k], px[k]), __fmul_rn(py[k], py[k])),
                    __fmul_rn(pz[k], pz[k]));
                float qp = __fadd_rn(
                    __fadd_rn(__fmul_rn(qx, px[k]), __fmul_rn(qy, py[k])),
                    __fmul_rn(qz, pz[k]));
                float d2 = __fsub_rn(__fadd_rn(q2, p2), __fmul_rn(2.0f, qp));
                bool pred = vld[k] && (d2 <= r2);
                unsigned long long b = __ballot(pred);
                if (storeMasks && hasQ && lane == 0)
                    masks[(long long)gw * nc + (it << 2) + k] = b;
                cnt += __popcll(b);
            }
        }
    }
    if (hasQ && lane == 0) counts[gw] = cnt;
}

// ---------------- K2: scan + dist-pad fill + mask pack ----------------
__global__ __launch_bounds__(256) void rs_write(
    const float* __restrict__ pts, const float* __restrict__ qs,
    const float* __restrict__ rad,
    const int* __restrict__ counts, const unsigned long long* __restrict__ masks,
    int useMasks,
    float* __restrict__ out_idx, float* __restrict__ out_splits,
    float* __restrict__ out_dist, long long MN, int N, int M) {
    __shared__ int s_scan[256];
    __shared__ int s_split[4097];  // M <= 4096
    int t = threadIdx.x;

    // per-block exclusive scan of counts[M]: 16 per thread + 256 ladder
    {
        int c[16];
        int sum = 0;
        int b16 = t * 16;
#pragma unroll
        for (int i = 0; i < 16; ++i) {
            int idx = b16 + i;
            int v = (idx < M) ? counts[idx] : 0;
            c[i] = sum;
            sum += v;
        }
        s_scan[t] = sum;
        __syncthreads();
        for (int off = 1; off < 256; off <<= 1) {
            int add = (t >= off) ? s_scan[t - off] : 0;
            __syncthreads();
            s_scan[t] += add;
            __syncthreads();
        }
        int excl = (t == 0) ? 0 : s_scan[t - 1];
#pragma unroll
        for (int i = 0; i < 16; ++i)
            if (b16 + i < M) s_split[b16 + i] = excl + c[i];
        if (t == 255) s_split[M] = excl + sum;
        __syncthreads();
    }

    if (blockIdx.x == 0) {
        for (int i = t; i <= M; i += 256) out_splits[i] = (float)s_split[i];
    }

    // ---- dist PAD fill [total, MN): fire-and-forget before pack ----
    {
        long long total = s_split[M];
        long long padLen = MN - total;
        if (padLen > 0) {
            long long tid = (long long)blockIdx.x * 256 + t;
            long long nth = (long long)gridDim.x * 256;
            fill_region(out_dist + total, padLen, 0.0f, tid, nth);
        }
    }

    int wv = t >> 6, lane = t & 63;
    int w = blockIdx.x * 4 + wv;  // one wave per query
    if (w >= M) return;
    float qxx = qs[3 * w], qyy = qs[3 * w + 1], qzz = qs[3 * w + 2];
    float q2 = __fadd_rn(__fadd_rn(__fmul_rn(qxx, qxx), __fmul_rn(qyy, qyy)),
                         __fmul_rn(qzz, qzz));
    long long base = s_split[w];
    int nc = N >> 6;

    if (useMasks) {
        const unsigned long long* mq = masks + (long long)w * nc;
        unsigned long long w0 = (lane < nc) ? mq[lane] : 0ull;
        unsigned long long w1 = (lane + 64 < nc) ? mq[lane + 64] : 0ull;
        int c0 = __popcll(w0), c1 = __popcll(w1);
        int i0 = c0, i1 = c1;
        for (int off = 1; off < 64; off <<= 1) {
            int t0 = __shfl_up(i0, off, 64);
            int t1 = __shfl_up(i1, off, 64);
            if (lane >= off) { i0 += t0; i1 += t1; }
        }
        int total0 = __shfl(i0, 63, 64);

        long long o = base + (i0 - c0);
        int pbase = lane << 6;
        unsigned long long mm = w0;
        while (mm) {
            int b = __ffsll((long long)mm) - 1;
            int p = pbase + b;
            float px = pts[3 * p], py = pts[3 * p + 1], pz = pts[3 * p + 2];
            float p2 = __fadd_rn(__fadd_rn(__fmul_rn(px, px), __fmul_rn(py, py)),
                                 __fmul_rn(pz, pz));
            float qp = __fadd_rn(__fadd_rn(__fmul_rn(qxx, px), __fmul_rn(qyy, py)),
                                 __fmul_rn(qzz, pz));
            float d2 = fmaxf(__fsub_rn(__fadd_rn(q2, p2), __fmul_rn(2.0f, qp)), 0.0f);
            out_idx[o] = (float)p;
            out_dist[o] = d2;
            ++o;
            mm &= mm - 1;
        }
        o = base + total0 + (i1 - c1);
        pbase = (lane + 64) << 6;
        mm = w1;
        while (mm) {
            int b = __ffsll((long long)mm) - 1;
            int p = pbase + b;
            float px = pts[3 * p], py = pts[3 * p + 1], pz = pts[3 * p + 2];
            float p2 = __fadd_rn(__fadd_rn(__fmul_rn(px, px), __fmul_rn(py, py)),
                                 __fmul_rn(pz, pz));
            float qp = __fadd_rn(__fadd_rn(__fmul_rn(qxx, px), __fmul_rn(qyy, py)),
                                 __fmul_rn(qzz, pz));
            float d2 = fmaxf(__fsub_rn(__fadd_rn(q2, p2), __fmul_rn(2.0f, qp)), 0.0f);
            out_idx[o] = (float)p;
            out_dist[o] = d2;
            ++o;
            mm &= mm - 1;
        }
    } else {
        // fallback: recompute + ballot pack (only if masks don't fit in ws)
        float r = rad[w];
        float r2 = __fmul_rn(r, r);
        int cum = 0;
        unsigned long long lanemask = (1ull << lane) - 1ull;
        for (int p0 = 0; p0 < N; p0 += 64) {
            int p = p0 + lane;
            float px = pts[3 * p], py = pts[3 * p + 1], pz = pts[3 * p + 2];
            float p2 = __fadd_rn(__fadd_rn(__fmul_rn(px, px), __fmul_rn(py, py)),
                                 __fmul_rn(pz, pz));
            float qp = __fadd_rn(__fadd_rn(__fmul_rn(qxx, px), __fmul_rn(qyy, py)),
                                 __fmul_rn(qzz, pz));
            float d2 = __fsub_rn(__fadd_rn(q2, p2), __fmul_rn(2.0f, qp));
            bool pred = (d2 <= r2);
            unsigned long long mask = __ballot(pred);
            if (pred) {
                long long pos = base + cum + __popcll(mask & lanemask);
                out_idx[pos] = (float)p;
                out_dist[pos] = fmaxf(d2, 0.0f);
            }
            cum += __popcll(mask);
        }
    }
}

extern "C" void kernel_launch(void* const* d_in, const int* in_sizes, int n_in,
                              void* d_out, int out_size, void* d_ws, size_t ws_size,
                              hipStream_t stream) {
    const float* points = (const float*)d_in[0];
    const float* queries = (const float*)d_in[1];
    const float* radii = (const float*)d_in[2];
    int N = in_sizes[0] / 3;
    int M = in_sizes[1] / 3;
    long long MN = (long long)M * (long long)N;

    float* out = (float*)d_out;
    float* out_idx = out;
    float* out_splits = out + MN;
    float* out_dist = out + MN + M + 1;

    // running-offset ws allocator (R2 lesson: never hand-sum offsets)
    char* ws = (char*)d_ws;
    size_t off = 0;
    auto take = [&](size_t bytes) -> size_t {
        size_t o = off;
        off += (bytes + 255) & ~(size_t)255;
        return o;
    };
    size_t o_counts = take((size_t)M * 4);
    size_t o_masks = take((size_t)M * (size_t)(N / 64) * 8);
    bool useMasks = (off <= ws_size) && ((N >> 6) <= 128);  // pack path needs nc<=128
    int* counts = (int*)(ws + o_counts);
    unsigned long long* masks = (unsigned long long*)(ws + o_masks);

    int C = (M + 3) / 4;  // 4 waves/block, 1 query/wave; waves also fill idx
    rs_fused<<<C, 256, 0, stream>>>(points, queries, radii, counts, masks,
                                    useMasks ? 1 : 0, out_idx, MN, N, M);
    int writeBlocks = (M + 3) / 4;  // 4 queries (waves) per 256-thr block
    rs_write<<<writeBlocks, 256, 0, stream>>>(points, queries, radii, counts, masks,
                                              useMasks ? 1 : 0, out_idx, out_splits,
                                              out_dist, MN, N, M);
}

// Round 12
// 58.905 us; speedup vs baseline: 1.2542x; 1.2542x over previous
//
#include <hip/hip_runtime.h>

// Radius search (L2^2), single segment, M=4096 queries x N=8192 points.
// Out (float32, concat): [0,MN) packed idx (pad -1) | [MN,MN+M+1) row splits |
//                        [MN+M+1, 2MN+M+1) packed d2 (pad 0).
// Exact numpy fp32 op order (NO fma):
//   q2=(qx*qx+qy*qy)+qz*qz ; p2=(px*px+py*py)+pz*pz ; qp=(qx*px+qy*py)+qz*pz
//   d2=max((q2+p2)-2*qp, 0) ; mask: d2<=r*r  (max irrelevant for mask, r2>0)
//
// Structure = R10 (64.1us verified; R11's fill-split regressed -> reverted):
//   K1: wave=query; count woven with BOTH pad fills (1 idx + 1 dist float4
//       store per iter). R12 change: count loads 4 consecutive pts/lane via
//       3x float4 (dense, 3 instrs vs 12 scalar); ballot replaced by nibble
//       (<<4*(lane&15)) + 16-lane OR-reduce -> bit-identical mask words.
//   K2: per-block redundant LDS scan of counts + mask pack (verified R8).

typedef float f32x4 __attribute__((ext_vector_type(4)));

// ---------------- K1: fused count (3xfloat4 loads) + woven pad-fill ----------------
__global__ __launch_bounds__(256) void rs_fused(
    const float* __restrict__ pts, const float* __restrict__ qs,
    const float* __restrict__ rad, int* __restrict__ counts,
    unsigned long long* __restrict__ masks, int storeMasks,
    float* __restrict__ out_idx, float* __restrict__ out_dist,
    long long MN, int N, int M) {
    int t = threadIdx.x;
    int wv = t >> 6, lane = t & 63;
    int gw = blockIdx.x * 4 + wv;       // wave id == query id
    int nWaves = gridDim.x * 4;

    bool hasQ = (gw < M);
    int qc = hasQ ? gw : 0;
    float qx = qs[3 * qc], qy = qs[3 * qc + 1], qz = qs[3 * qc + 2];
    float q2 = __fadd_rn(__fadd_rn(__fmul_rn(qx, qx), __fmul_rn(qy, qy)),
                         __fmul_rn(qz, qz));
    float r = rad[qc];
    float r2 = hasQ ? __fmul_rn(r, r) : -1.0f;  // raw d2 > -1 always

    int nc = N >> 6;                      // 64-pt mask words
    int vecIters = N >> 8;                // 256 pts/iter (4 consecutive/lane)
    long long V = MN >> 2;                // MN % 4 == 0 in harness
    long long perWave = (V + nWaves - 1) / nWaves;
    int fillIters = (int)((perWave + 63) >> 6);
    long long fbase = (long long)gw * perWave;
    long long fend = fbase + perWave;
    if (fend > V) fend = V;
    f32x4* vidx = (f32x4*)out_idx;
    f32x4* vdst = (f32x4*)out_dist;
    f32x4 vm1 = {-1.0f, -1.0f, -1.0f, -1.0f};
    f32x4 vz = {0.0f, 0.0f, 0.0f, 0.0f};

    int iters = vecIters > fillIters ? vecIters : fillIters;
    int cntLane = 0;
    int shift = (lane & 15) << 2;
    int wordSel = lane >> 4;  // which of the 4 mask words this lane's group owns

    for (int it = 0; it < iters; ++it) {
        // ---- fill step: fire-and-forget coalesced stores ----
        if (it < fillIters) {
            long long fi = fbase + (long long)it * 64 + lane;
            if (fi < fend) { vidx[fi] = vm1; vdst[fi] = vz; }
        }
        // ---- count step: 4 consecutive points/lane via 3x float4 ----
        if (it < vecIters) {
            const f32x4* pv = (const f32x4*)(pts + (size_t)it * 768);
            f32x4 v0 = pv[3 * lane + 0];
            f32x4 v1 = pv[3 * lane + 1];
            f32x4 v2 = pv[3 * lane + 2];
            float px[4] = {v0.x, v0.w, v1.z, v2.y};
            float py[4] = {v0.y, v1.x, v1.w, v2.z};
            float pz[4] = {v0.z, v1.y, v2.x, v2.w};
            unsigned nib = 0;
#pragma unroll
            for (int k = 0; k < 4; ++k) {
                float p2 = __fadd_rn(
                    __fadd_rn(__fmul_rn(px[k], px[k]), __fmul_rn(py[k], py[k])),
                    __fmul_rn(pz[k], pz[k]));
                float qp = __fadd_rn(
                    __fadd_rn(__fmul_rn(qx, px[k]), __fmul_rn(qy, py[k])),
                    __fmul_rn(qz, pz[k]));
                float d2 = __fsub_rn(__fadd_rn(q2, p2), __fmul_rn(2.0f, qp));
                bool pred = (d2 <= r2);
                nib |= (pred ? 1u : 0u) << k;
                cntLane += pred ? 1 : 0;
            }
            // build the 4 mask words: OR-reduce nibble<<shift in 16-lane groups
            unsigned long long contrib = (unsigned long long)nib << shift;
#pragma unroll
            for (int s = 1; s < 16; s <<= 1) contrib |= __shfl_xor(contrib, s, 64);
            if (storeMasks && hasQ && (lane & 15) == 0)
                masks[(long long)gw * nc + (it << 2) + wordSel] = contrib;
        }
    }
    // ---- tail (N % 256 != 0): strided scalar + ballot path ----
    for (int c = vecIters << 2; c < nc; ++c) {
        int p = (c << 6) + lane;
        bool vld = (p < N);
        int pcl = vld ? p : 0;
        float px = pts[3 * pcl], py = pts[3 * pcl + 1], pz = pts[3 * pcl + 2];
        float p2 = __fadd_rn(__fadd_rn(__fmul_rn(px, px), __fmul_rn(py, py)),
                             __fmul_rn(pz, pz));
        float qp = __fadd_rn(__fadd_rn(__fmul_rn(qx, px), __fmul_rn(qy, py)),
                             __fmul_rn(qz, pz));
        float d2 = __fsub_rn(__fadd_rn(q2, p2), __fmul_rn(2.0f, qp));
        bool pred = vld && (d2 <= r2);
        unsigned long long b = __ballot(pred);
        if (storeMasks && hasQ && lane == 0) masks[(long long)gw * nc + c] = b;
        cntLane += pred ? 1 : 0;
    }
    // wave-reduce the per-lane counts
    for (int off = 32; off > 0; off >>= 1) cntLane += __shfl_down(cntLane, off, 64);
    if (hasQ && lane == 0) counts[gw] = cntLane;
}

// ---------------- K2: redundant cheap scan + mask pack (R10 verified) ----------------
__global__ __launch_bounds__(256) void rs_write(
    const float* __restrict__ pts, const float* __restrict__ qs,
    const float* __restrict__ rad,
    const int* __restrict__ counts, const unsigned long long* __restrict__ masks,
    int useMasks,
    float* __restrict__ out_idx, float* __restrict__ out_splits,
    float* __restrict__ out_dist, int N, int M) {
    __shared__ int s_scan[256];
    __shared__ int s_split[4097];  // M <= 4096
    int t = threadIdx.x;

    // per-block exclusive scan of counts[M]: 16 per thread + 256 ladder
    {
        int c[16];
        int sum = 0;
        int b16 = t * 16;
#pragma unroll
        for (int i = 0; i < 16; ++i) {
            int idx = b16 + i;
            int v = (idx < M) ? counts[idx] : 0;
            c[i] = sum;
            sum += v;
        }
        s_scan[t] = sum;
        __syncthreads();
        for (int off = 1; off < 256; off <<= 1) {
            int add = (t >= off) ? s_scan[t - off] : 0;
            __syncthreads();
            s_scan[t] += add;
            __syncthreads();
        }
        int excl = (t == 0) ? 0 : s_scan[t - 1];
#pragma unroll
        for (int i = 0; i < 16; ++i)
            if (b16 + i < M) s_split[b16 + i] = excl + c[i];
        if (t == 255) s_split[M] = excl + sum;
        __syncthreads();
    }

    if (blockIdx.x == 0) {
        for (int i = t; i <= M; i += 256) out_splits[i] = (float)s_split[i];
    }

    int wv = t >> 6, lane = t & 63;
    int w = blockIdx.x * 4 + wv;  // one wave per query
    if (w >= M) return;
    float qxx = qs[3 * w], qyy = qs[3 * w + 1], qzz = qs[3 * w + 2];
    float q2 = __fadd_rn(__fadd_rn(__fmul_rn(qxx, qxx), __fmul_rn(qyy, qyy)),
                         __fmul_rn(qzz, qzz));
    long long base = s_split[w];
    int nc = N >> 6;

    if (useMasks) {
        const unsigned long long* mq = masks + (long long)w * nc;
        unsigned long long w0 = (lane < nc) ? mq[lane] : 0ull;
        unsigned long long w1 = (lane + 64 < nc) ? mq[lane + 64] : 0ull;
        int c0 = __popcll(w0), c1 = __popcll(w1);
        int i0 = c0, i1 = c1;
        for (int off = 1; off < 64; off <<= 1) {
            int t0 = __shfl_up(i0, off, 64);
            int t1 = __shfl_up(i1, off, 64);
            if (lane >= off) { i0 += t0; i1 += t1; }
        }
        int total0 = __shfl(i0, 63, 64);

        long long o = base + (i0 - c0);
        int pbase = lane << 6;
        unsigned long long mm = w0;
        while (mm) {
            int b = __ffsll((long long)mm) - 1;
            int p = pbase + b;
            float px = pts[3 * p], py = pts[3 * p + 1], pz = pts[3 * p + 2];
            float p2 = __fadd_rn(__fadd_rn(__fmul_rn(px, px), __fmul_rn(py, py)),
                                 __fmul_rn(pz, pz));
            float qp = __fadd_rn(__fadd_rn(__fmul_rn(qxx, px), __fmul_rn(qyy, py)),
                                 __fmul_rn(qzz, pz));
            float d2 = fmaxf(__fsub_rn(__fadd_rn(q2, p2), __fmul_rn(2.0f, qp)), 0.0f);
            out_idx[o] = (float)p;
            out_dist[o] = d2;
            ++o;
            mm &= mm - 1;
        }
        o = base + total0 + (i1 - c1);
        pbase = (lane + 64) << 6;
        mm = w1;
        while (mm) {
            int b = __ffsll((long long)mm) - 1;
            int p = pbase + b;
            float px = pts[3 * p], py = pts[3 * p + 1], pz = pts[3 * p + 2];
            float p2 = __fadd_rn(__fadd_rn(__fmul_rn(px, px), __fmul_rn(py, py)),
                                 __fmul_rn(pz, pz));
            float qp = __fadd_rn(__fadd_rn(__fmul_rn(qxx, px), __fmul_rn(qyy, py)),
                                 __fmul_rn(qzz, pz));
            float d2 = fmaxf(__fsub_rn(__fadd_rn(q2, p2), __fmul_rn(2.0f, qp)), 0.0f);
            out_idx[o] = (float)p;
            out_dist[o] = d2;
            ++o;
            mm &= mm - 1;
        }
    } else {
        // fallback: recompute + ballot pack (only if masks don't fit in ws)
        float r = rad[w];
        float r2 = __fmul_rn(r, r);
        int cum = 0;
        unsigned long long lanemask = (1ull << lane) - 1ull;
        for (int p0 = 0; p0 < N; p0 += 64) {
            int p = p0 + lane;
            float px = pts[3 * p], py = pts[3 * p + 1], pz = pts[3 * p + 2];
            float p2 = __fadd_rn(__fadd_rn(__fmul_rn(px, px), __fmul_rn(py, py)),
                                 __fmul_rn(pz, pz));
            float qp = __fadd_rn(__fadd_rn(__fmul_rn(qxx, px), __fmul_rn(qyy, py)),
                                 __fmul_rn(qzz, pz));
            float d2 = __fsub_rn(__fadd_rn(q2, p2), __fmul_rn(2.0f, qp));
            bool pred = (d2 <= r2);
            unsigned long long mask = __ballot(pred);
            if (pred) {
                long long pos = base + cum + __popcll(mask & lanemask);
                out_idx[pos] = (float)p;
                out_dist[pos] = fmaxf(d2, 0.0f);
            }
            cum += __popcll(mask);
        }
    }
}

extern "C" void kernel_launch(void* const* d_in, const int* in_sizes, int n_in,
                              void* d_out, int out_size, void* d_ws, size_t ws_size,
                              hipStream_t stream) {
    const float* points = (const float*)d_in[0];
    const float* queries = (const float*)d_in[1];
    const float* radii = (const float*)d_in[2];
    int N = in_sizes[0] / 3;
    int M = in_sizes[1] / 3;
    long long MN = (long long)M * (long long)N;

    float* out = (float*)d_out;
    float* out_idx = out;
    float* out_splits = out + MN;
    float* out_dist = out + MN + M + 1;

    // running-offset ws allocator (R2 lesson: never hand-sum offsets)
    char* ws = (char*)d_ws;
    size_t off = 0;
    auto take = [&](size_t bytes) -> size_t {
        size_t o = off;
        off += (bytes + 255) & ~(size_t)255;
        return o;
    };
    size_t o_counts = take((size_t)M * 4);
    size_t o_masks = take((size_t)M * (size_t)(N / 64) * 8);
    bool useMasks = (off <= ws_size) && ((N >> 6) <= 128);  // pack path needs nc<=128
    int* counts = (int*)(ws + o_counts);
    unsigned long long* masks = (unsigned long long*)(ws + o_masks);

    int C = (M + 3) / 4;  // 4 waves/block, 1 query/wave; waves also fill
    rs_fused<<<C, 256, 0, stream>>>(points, queries, radii, counts, masks,
                                    useMasks ? 1 : 0, out_idx, out_dist, MN, N, M);
    int writeBlocks = (M + 3) / 4;  // 4 queries (waves) per 256-thr block
    rs_write<<<writeBlocks, 256, 0, stream>>>(points, queries, radii, counts, masks,
                                              useMasks ? 1 : 0, out_idx, out_splits,
                                              out_dist, N, M);
}